// Round 6
// baseline (882.385 us; speedup 1.0000x reference)
//
#include <hip/hip_runtime.h>

// GraphConvolution: out = relu(bias + sum_k S_k @ (x @ W_k))
// B=4, N=50000, F_IN=F_OUT=64, K=4, E=800000
//
// Reassociated: out = relu(bias + sum_k (S_k @ x) @ W_k).
//  1. pack x -> xb[n][b][f] bf16 (one shared 25.6 MB gather source for all k)
//  2. counting-sort edges by (k, row, col-chunk) -> col-sorted CSR, packed
//     payload u32 = col<<16 | bf16(val)
//  3. gather_gemm: wave per row, acc[k] in regs (all 4 supports, one xb
//     sweep, wave-uniform csr reads); epilogue = LDS GEMM over (k,f) with
//     bf16 W + bias + relu, writes out once. No atomics anywhere.

#define FDIM 64
#define CHUNK_SHIFT 12   // col-chunk = col >> 12 (4096 cols = 2.1 MB xb slice)

__device__ __forceinline__ unsigned short bf16_rne(float v) {
    unsigned u = __float_as_uint(v);
    return (unsigned short)((u + 0x7FFFu + ((u >> 16) & 1u)) >> 16);
}

// ---------------------------------------------------------------------------
// pack x[b][n][f] f32 -> xb[n][b][f] bf16 (512 B per node, wave-read friendly)
// ---------------------------------------------------------------------------
__global__ __launch_bounds__(256) void pack_x(
    const float* __restrict__ x, unsigned short* __restrict__ xb,
    int M, int N)
{
    int i = blockIdx.x * 256 + threadIdx.x;
    if (i >= M * 16) return;
    int f4 = i & 15;
    int bn = i >> 4;
    int b = bn / N;
    int n = bn - b * N;
    float4 v = ((const float4*)x)[i];
    ushort4 p;
    p.x = bf16_rne(v.x); p.y = bf16_rne(v.y);
    p.z = bf16_rne(v.z); p.w = bf16_rne(v.w);
    *(ushort4*)(xb + (size_t)n * 256 + b * 64 + f4 * 4) = p;
}

// ---------------------------------------------------------------------------
// 2-level histogram: counts2[(k*N + row)*CNUM + (col>>CHUNK_SHIFT)]
// ---------------------------------------------------------------------------
__global__ __launch_bounds__(256) void hist2(
    const int* __restrict__ rows, const int* __restrict__ cols,
    int* __restrict__ counts2, int total, int E, int N, int CNUM)
{
    int i = blockIdx.x * 256 + threadIdx.x;
    if (i >= total) return;
    int k = i / E;
    int idx = (k * N + rows[i]) * CNUM + (cols[i] >> CHUNK_SHIFT);
    atomicAdd(&counts2[idx], 1);
}

// ---------------------------------------------------------------------------
// generic scan chain (used flat: K=1, N=L)
// ---------------------------------------------------------------------------
__global__ __launch_bounds__(256) void scan_block_sums(
    const int* __restrict__ counts, int* __restrict__ bsums, int N, int nb)
{
    int k = blockIdx.x / nb, j = blockIdx.x % nb;
    int t = threadIdx.x, lane = t & 63, w = t >> 6;
    int i = j * 256 + t;
    int v = (i < N) ? counts[k * N + i] : 0;
#pragma unroll
    for (int off = 32; off; off >>= 1) v += __shfl_down(v, off);
    __shared__ int lds[4];
    if (lane == 0) lds[w] = v;
    __syncthreads();
    if (t == 0) bsums[k * nb + j] = lds[0] + lds[1] + lds[2] + lds[3];
}

__global__ __launch_bounds__(256) void scan_bsums(int* bsums, int nb, int K)
{
    __shared__ int lds[4];
    __shared__ int carry;
    int t = threadIdx.x, lane = t & 63, w = t >> 6;
    for (int k = 0; k < K; ++k) {
        if (t == 0) carry = 0;
        __syncthreads();
        for (int base = 0; base < nb; base += 256) {
            int i = base + t;
            int v = (i < nb) ? bsums[k * nb + i] : 0;
            int x = v;
#pragma unroll
            for (int off = 1; off < 64; off <<= 1) {
                int y = __shfl_up(x, off);
                if (lane >= off) x += y;
            }
            if (lane == 63) lds[w] = x;
            __syncthreads();
            int wo = 0;
            for (int q = 0; q < w; ++q) wo += lds[q];
            int excl = carry + wo + x - v;
            if (i < nb) bsums[k * nb + i] = excl;
            __syncthreads();
            if (t == 255) carry = carry + wo + x;
            __syncthreads();
        }
    }
}

// writes ptr[i+1] = incl scan; ptr[0] = 0 (flat: k = 0)
__global__ __launch_bounds__(256) void scan_write_ptr(
    const int* __restrict__ counts, const int* __restrict__ bsums,
    int* __restrict__ ptr, int N, int nb)
{
    int k = blockIdx.x / nb, j = blockIdx.x % nb;
    int t = threadIdx.x, lane = t & 63, w = t >> 6;
    int i = j * 256 + t;
    int v = (i < N) ? counts[k * N + i] : 0;
    int x = v;
#pragma unroll
    for (int off = 1; off < 64; off <<= 1) {
        int y = __shfl_up(x, off);
        if (lane >= off) x += y;
    }
    __shared__ int lds[4];
    if (lane == 63) lds[w] = x;
    __syncthreads();
    int wo = 0;
    for (int q = 0; q < w; ++q) wo += lds[q];
    int incl = wo + x;
    if (i < N) ptr[k * (N + 1) + i + 1] = bsums[k * nb + j] + incl;
    if (t == 0 && j == 0) ptr[k * (N + 1)] = 0;
}

// ---------------------------------------------------------------------------
// fill: counts2 still holds original counts; atomicSub hands out slots.
// ---------------------------------------------------------------------------
__global__ __launch_bounds__(256) void fill2(
    const int* __restrict__ rows, const int* __restrict__ cols,
    const float* __restrict__ vals, const int* __restrict__ seg_ptr,
    int* __restrict__ counts2, unsigned* __restrict__ csr,
    int total, int E, int N, int CNUM)
{
    int i = blockIdx.x * 256 + threadIdx.x;
    if (i >= total) return;
    int k = i / E;
    int col = cols[i];
    int idx = (k * N + rows[i]) * CNUM + (col >> CHUNK_SHIFT);
    int old = atomicSub(&counts2[idx], 1);
    int slot = seg_ptr[idx] + old - 1;
    csr[slot] = ((unsigned)col << 16) | (unsigned)bf16_rne(vals[i]);
}

// ---------------------------------------------------------------------------
// fused gather + GEMM + bias + relu.  4 waves/block, wave per row.
// Gather: lane=(b,f4); per edge one wave-uniform csr u32 + one 512 B xb read.
// Epilogue: acc -> LDS, lane=(b,g4) computes 256-long (k,f) dot with bf16 W.
// ---------------------------------------------------------------------------
__global__ __launch_bounds__(256) void gather_gemm(
    const unsigned short* __restrict__ xb,
    const int* __restrict__ seg_ptr,
    const unsigned* __restrict__ csr,
    const float* __restrict__ kernels,
    const float* __restrict__ bias,
    float* __restrict__ out,
    int N, int CNUM)
{
    __shared__ unsigned short Wl[256 * 64];   // [k*64+f][g] bf16, 32 KB
    __shared__ float accS[4][4][260];         // [wave][b][k*64+f], 16.6 KB

    const int t = threadIdx.x;

    // stage W: 4x64x64 f32 -> bf16 (4096 float4, 16 per thread)
#pragma unroll
    for (int i = 0; i < 16; ++i) {
        int idx = t + 256 * i;
        float4 v = ((const float4*)kernels)[idx];
        ushort4 p;
        p.x = bf16_rne(v.x); p.y = bf16_rne(v.y);
        p.z = bf16_rne(v.z); p.w = bf16_rne(v.w);
        ((ushort4*)Wl)[idx] = p;
    }
    __syncthreads();

    const int w = t >> 6, lane = t & 63;
    const int row = blockIdx.x * 4 + w;
    const int b = lane >> 4;
    const int q4 = lane & 15;        // f4 during gather, g4 during epilogue

    if (row < N) {
        const unsigned short* xbl = xb + lane * 4;
        float4 acc[4];
#pragma unroll
        for (int k = 0; k < 4; ++k) acc[k] = make_float4(0.f, 0.f, 0.f, 0.f);

#pragma unroll
        for (int k = 0; k < 4; ++k) {
            const int e0 = seg_ptr[(k * N + row) * CNUM];
            const int e1 = seg_ptr[(k * N + row + 1) * CNUM];
#pragma unroll 8
            for (int j = e0; j < e1; ++j) {
                unsigned ww = csr[j];             // wave-uniform, L1-hot
                int col = ww >> 16;
                float val = __uint_as_float(ww << 16);
                uint2 hv = *(const uint2*)(xbl + (size_t)col * 256);
                float f0 = __uint_as_float(hv.x << 16);
                float f1 = __uint_as_float(hv.x & 0xFFFF0000u);
                float f2 = __uint_as_float(hv.y << 16);
                float f3 = __uint_as_float(hv.y & 0xFFFF0000u);
                acc[k].x = fmaf(f0, val, acc[k].x);
                acc[k].y = fmaf(f1, val, acc[k].y);
                acc[k].z = fmaf(f2, val, acc[k].z);
                acc[k].w = fmaf(f3, val, acc[k].w);
            }
        }

#pragma unroll
        for (int k = 0; k < 4; ++k)
            *(float4*)&accS[w][b][k * 64 + q4 * 4] = acc[k];
    }
    __syncthreads();   // accS ready (also orders vs any cross-wave reuse)

    if (row < N) {
        float4 o = make_float4(0.f, 0.f, 0.f, 0.f);
#pragma unroll 4
        for (int kf = 0; kf < 256; ++kf) {
            float a = accS[w][b][kf];
            ushort4 wv = *(const ushort4*)&Wl[kf * 64 + q4 * 4];
            o.x = fmaf(a, __uint_as_float((unsigned)wv.x << 16), o.x);
            o.y = fmaf(a, __uint_as_float((unsigned)wv.y << 16), o.y);
            o.z = fmaf(a, __uint_as_float((unsigned)wv.z << 16), o.z);
            o.w = fmaf(a, __uint_as_float((unsigned)wv.w << 16), o.w);
        }
        float4 bi = ((const float4*)bias)[q4];
        o.x = fmaxf(o.x + bi.x, 0.f);
        o.y = fmaxf(o.y + bi.y, 0.f);
        o.z = fmaxf(o.z + bi.z, 0.f);
        o.w = fmaxf(o.w + bi.w, 0.f);
        *(float4*)(out + ((size_t)b * N + row) * 64 + q4 * 4) = o;
    }
}

// ---------------------------------------------------------------------------
// Tier-3 fallback (round-1 proven): f32 gemm + atomic scatter + bias_relu.
// ---------------------------------------------------------------------------
__global__ __launch_bounds__(256) void gemm64(
    const float* __restrict__ x, const float* __restrict__ W,
    float* __restrict__ h, int M)
{
    __shared__ float xs[64][68];
    __shared__ float Wl[64][64];
    const int t = threadIdx.x;
    {
        const float4* Wv = (const float4*)W;
        float4* Wd = (float4*)&Wl[0][0];
#pragma unroll
        for (int i = 0; i < 4; ++i) Wd[t + 256 * i] = Wv[t + 256 * i];
    }
    const int row0 = blockIdx.x * 64;
#pragma unroll
    for (int i = 0; i < 4; ++i) {
        int idx = t + 256 * i;
        int r = idx >> 4;
        int c4 = idx & 15;
        float4 v = ((const float4*)(x + (size_t)(row0 + r) * FDIM))[c4];
        int f = c4 * 4;
        xs[f + 0][r] = v.x; xs[f + 1][r] = v.y;
        xs[f + 2][r] = v.z; xs[f + 3][r] = v.w;
    }
    __syncthreads();
    const int r0 = (t >> 4) * 4;
    const int g0 = (t & 15) * 4;
    float acc[4][4];
#pragma unroll
    for (int i = 0; i < 4; ++i)
#pragma unroll
        for (int j = 0; j < 4; ++j) acc[i][j] = 0.f;
#pragma unroll
    for (int f = 0; f < 64; ++f) {
        float4 xv = *(const float4*)&xs[f][r0];
        float4 wv = *(const float4*)&Wl[f][g0];
        acc[0][0] = fmaf(xv.x, wv.x, acc[0][0]); acc[0][1] = fmaf(xv.x, wv.y, acc[0][1]);
        acc[0][2] = fmaf(xv.x, wv.z, acc[0][2]); acc[0][3] = fmaf(xv.x, wv.w, acc[0][3]);
        acc[1][0] = fmaf(xv.y, wv.x, acc[1][0]); acc[1][1] = fmaf(xv.y, wv.y, acc[1][1]);
        acc[1][2] = fmaf(xv.y, wv.z, acc[1][2]); acc[1][3] = fmaf(xv.y, wv.w, acc[1][3]);
        acc[2][0] = fmaf(xv.z, wv.x, acc[2][0]); acc[2][1] = fmaf(xv.z, wv.y, acc[2][1]);
        acc[2][2] = fmaf(xv.z, wv.z, acc[2][2]); acc[2][3] = fmaf(xv.z, wv.w, acc[2][3]);
        acc[3][0] = fmaf(xv.w, wv.x, acc[3][0]); acc[3][1] = fmaf(xv.w, wv.y, acc[3][1]);
        acc[3][2] = fmaf(xv.w, wv.z, acc[3][2]); acc[3][3] = fmaf(xv.w, wv.w, acc[3][3]);
    }
#pragma unroll
    for (int i = 0; i < 4; ++i)
        *(float4*)(h + (size_t)(row0 + r0 + i) * FDIM + g0) =
            make_float4(acc[i][0], acc[i][1], acc[i][2], acc[i][3]);
}

__global__ __launch_bounds__(256) void scatter_edges(
    const float* __restrict__ h, const int* __restrict__ rows,
    const int* __restrict__ cols, const float* __restrict__ vals,
    float* __restrict__ out, int E, int N)
{
    const int e = (blockIdx.x << 2) | (threadIdx.x >> 6);
    if (e >= E) return;
    const int lane = threadIdx.x & 63;
    const int row = __builtin_amdgcn_readfirstlane(rows[e]);
    const int col = __builtin_amdgcn_readfirstlane(cols[e]);
    const float val =
        __uint_as_float(__builtin_amdgcn_readfirstlane(__float_as_uint(vals[e])));
    const size_t stride = (size_t)N * FDIM;
    size_t cbase = (size_t)col * FDIM + lane;
    size_t rbase = (size_t)row * FDIM + lane;
#pragma unroll
    for (int b = 0; b < 4; ++b) {
        float hv = h[cbase + (size_t)b * stride];
        atomicAdd(out + rbase + (size_t)b * stride, hv * val);
    }
}

__global__ __launch_bounds__(256) void bias_relu(
    float* __restrict__ out, const float* __restrict__ bias, size_t total4)
{
    size_t i = (size_t)blockIdx.x * blockDim.x + threadIdx.x;
    if (i >= total4) return;
    float4 v = ((float4*)out)[i];
    float4 b = ((const float4*)bias)[i & 15];
    v.x = fmaxf(v.x + b.x, 0.f); v.y = fmaxf(v.y + b.y, 0.f);
    v.z = fmaxf(v.z + b.z, 0.f); v.w = fmaxf(v.w + b.w, 0.f);
    ((float4*)out)[i] = v;
}

extern "C" void kernel_launch(void* const* d_in, const int* in_sizes, int n_in,
                              void* d_out, int out_size, void* d_ws, size_t ws_size,
                              hipStream_t stream) {
    const float* x       = (const float*)d_in[0];
    const int*   rows    = (const int*)d_in[1];
    const int*   cols    = (const int*)d_in[2];
    const float* vals    = (const float*)d_in[3];
    const float* kernels = (const float*)d_in[4];
    const float* bias    = (const float*)d_in[5];

    float* out = (float*)d_out;

    const int K = in_sizes[4] / (FDIM * FDIM);      // 4
    const int E = in_sizes[1] / K;                  // 800000
    const int M = in_sizes[0] / FDIM;               // B*N = 200000
    const int N = M / 4;                            // 50000 (B=4)
    const int total = K * E;

    const int CNUM = (N + (1 << CHUNK_SHIFT) - 1) >> CHUNK_SHIFT;   // 13
    const long long L = (long long)K * N * CNUM;                    // 2.6M
    const int nb2 = (int)((L + 255) / 256);

    const size_t al = 15;
    const size_t xbB  = (((size_t)N * 512) + al) & ~al;             // 25.6 MB
    const size_t csrB = (((size_t)total * 4) + al) & ~al;           // 12.8 MB
    const size_t segB = (((size_t)(L + 1) * 4) + al) & ~al;         // 10.4 MB
    const size_t cntB = (((size_t)L * 4) + al) & ~al;               // 10.4 MB
    const size_t bsB  = (((size_t)nb2 * 4) + al) & ~al;
    const size_t needed = xbB + csrB + segB + cntB + bsB;

    const bool fast = (K == 4) && (N <= 65536) && (M == 4 * N) &&
                      (ws_size >= needed) && (L < (1LL << 31));

    if (fast) {
        char* ws = (char*)d_ws;
        unsigned short* xb  = (unsigned short*)ws;  ws += xbB;
        unsigned* csr       = (unsigned*)ws;        ws += csrB;
        int* seg_ptr        = (int*)ws;             ws += segB;
        int* counts2        = (int*)ws;             ws += cntB;
        int* bsums2         = (int*)ws;

        pack_x<<<(M * 16 + 255) / 256, 256, 0, stream>>>(x, xb, M, N);

        hipMemsetAsync(counts2, 0, (size_t)L * 4, stream);
        hist2<<<(total + 255) / 256, 256, 0, stream>>>(
            rows, cols, counts2, total, E, N, CNUM);
        scan_block_sums<<<nb2, 256, 0, stream>>>(counts2, bsums2, (int)L, nb2);
        scan_bsums<<<1, 256, 0, stream>>>(bsums2, nb2, 1);
        scan_write_ptr<<<nb2, 256, 0, stream>>>(counts2, bsums2, seg_ptr, (int)L, nb2);
        fill2<<<(total + 255) / 256, 256, 0, stream>>>(
            rows, cols, vals, seg_ptr, counts2, csr, total, E, N, CNUM);

        gather_gemm<<<(N + 3) / 4, 256, 0, stream>>>(
            xb, seg_ptr, csr, kernels, bias, out, N, CNUM);
    } else {
        // Tier-3 fallback: atomic scatter (round-1 proven)
        float* h = (float*)d_ws;
        hipMemsetAsync(out, 0, (size_t)out_size * sizeof(float), stream);
        for (int k = 0; k < K; ++k) {
            gemm64<<<M / 64, 256, 0, stream>>>(
                x, kernels + (size_t)k * FDIM * FDIM, h, M);
            scatter_edges<<<(E + 3) / 4, 256, 0, stream>>>(
                h, rows + (size_t)k * E, cols + (size_t)k * E,
                vals + (size_t)k * E, out, E, N);
        }
        const size_t total4 = (size_t)out_size / 4;
        bias_relu<<<(int)((total4 + 255) / 256), 256, 0, stream>>>(out, bias, total4);
    }
}